// Round 1
// 1116.385 us; speedup vs baseline: 1.0332x; 1.0332x over previous
//
#include <hip/hip_runtime.h>

typedef __attribute__((ext_vector_type(8))) short short8;
typedef __attribute__((ext_vector_type(4))) float floatx4;

#define DEVI __device__ __forceinline__

// direct global->LDS, 16B per lane; LDS dest = wave-uniform base + lane*16
#define GLL(g, l) __builtin_amdgcn_global_load_lds(                      \
    (const __attribute__((address_space(1))) void*)(g),                  \
    (__attribute__((address_space(3))) void*)(l), 16, 0, 0)

// ---------------- level constants ----------------
constexpr int LC[6]   = {512, 1024, 512, 256, 256, 256};   // in channels
constexpr int LS[6]   = {38, 19, 10, 5, 3, 1};             // spatial
constexpr int LA[6]   = {4, 6, 6, 6, 4, 4};                // anchors
constexpr int LROW[6] = {0, 5776, 7942, 8542, 8692, 8728}; // row offsets into 8732
constexpr long FOFF[6] = {0, 23658496, 35487744, 37126144, 37330944, 37404672}; // featT elem offsets
constexpr long WCBASE  = 37412864;                                              // Wc elem base
constexpr long WOFF[6] = {0, 1751040, 7004160, 9630720, 10944000, 11819520};    // Wc per-level offsets
constexpr int  GOFF[7] = {0, 218880, 875520, 1203840, 1368000, 1477440, 1586880}; // groups of 8
constexpr long ZOFF    = 50107904;   // zero-sentinel page (elems)
constexpr int  ZSIZE   = 1088;
constexpr long CLSOFF  = 1117696;    // 32*8732*4
constexpr size_t WS_NEEDED = (size_t)(ZOFF + ZSIZE) * 2;

DEVI short f2bf(float f) {
    union { float f; unsigned u; } x; x.f = f;
    unsigned u = x.u + 0x7fffu + ((x.u >> 16) & 1u);   // RNE
    return (short)(u >> 16);
}

// ---------------- transpose feat [n,c,pix] f32 -> [n,pix,c] bf16 ----------------
template<int L>
__global__ void transpose_feat(const float* __restrict__ feat, short* __restrict__ ft) {
    constexpr int C = LC[L], S = LS[L], HW = S * S;
    const int n  = blockIdx.z;
    const int p0 = blockIdx.x * 64;
    const int c0 = blockIdx.y * 64;
    __shared__ float tile[64][65];
    const int t = threadIdx.x;
    const float* fb = feat + ((size_t)n * C + c0) * HW;
#pragma unroll
    for (int e = 0; e < 16; ++e) {
        int idx = e * 256 + t;
        int p = idx & 63, cc = idx >> 6;
        int pix = p0 + p;
        tile[cc][p] = (pix < HW) ? fb[(size_t)cc * HW + pix] : 0.f;
    }
    __syncthreads();
    short* ob = ft + ((size_t)n * HW) * C + c0;
#pragma unroll
    for (int e = 0; e < 16; ++e) {
        int idx = e * 256 + t;
        int cc = idx & 63, p = idx >> 6;
        int pix = p0 + p;
        if (pix < HW) ob[(size_t)pix * C + cc] = f2bf(tile[cc][p]);
    }
}

// ---------------- reorder weights: combined [o][k=r*C+c] bf16; also zero-fill sentinel ----------------
struct WPtrs { const float* cw[6]; const float* rw[6]; };

__global__ void reorder_weights(WPtrs p, short* __restrict__ wc, short* __restrict__ zb) {
    int g = blockIdx.x * 256 + threadIdx.x;
    if (g >= GOFF[6]) {
        if (blockIdx.x == 6199 && threadIdx.x < ZSIZE / 8) {
            short8 z;
#pragma unroll
            for (int q = 0; q < 8; ++q) z[q] = 0;
            *(short8*)(zb + threadIdx.x * 8) = z;
        }
        return;
    }
    int L = 0;
#pragma unroll
    for (int q = 1; q < 6; ++q) if (g >= GOFF[q]) L = q;
    int e = g - GOFF[L];
    const int C = LC[L], A = LA[L];
    const unsigned K8 = (unsigned)(9 * C) >> 3, C8 = (unsigned)C >> 3;
    unsigned o    = (unsigned)e / K8;
    unsigned remk = (unsigned)e - o * K8;
    unsigned r    = remk / C8;
    unsigned c    = (remk - r * C8) << 3;
    int A4 = A << 2;
    const float* src = ((int)o < A4) ? (p.rw[L] + (size_t)o * 9 * C)
                                     : (p.cw[L] + (size_t)(o - A4) * 9 * C);
    short8 v;
#pragma unroll
    for (int j = 0; j < 8; ++j) v[j] = f2bf(src[(size_t)(c + j) * 9 + r]);
    *(short8*)(wc + (size_t)WOFF[L] + (size_t)o * (9 * C) + (size_t)r * C + c) = v;
}

// ---------------- implicit-GEMM conv: dbuf-pipelined 128x128x32, XOR-swizzled LDS ----------------
template<int L>
__global__ __launch_bounds__(256, 4)
void gemm_level(const short* __restrict__ ft, const short* __restrict__ wc,
                const short* __restrict__ zb,
                const float* __restrict__ cls_b, const float* __restrict__ reg_b,
                float* __restrict__ out)
{
    constexpr int C = LC[L], S = LS[L], A = LA[L];
    constexpr int HW = S * S, M = 32 * HW, K = 9 * C, O = 95 * A;
    constexpr int ROWOFF = LROW[L], A4 = 4 * A;
    constexpr int NM = (M + 127) / 128, NB = (O + 127) / 128;
    constexpr int TOT = NM * NB, TPX = (TOT + 7) / 8;
    constexpr int KC  = C / 32;                               // k-chunks per tap
    constexpr int LKC = (C == 1024) ? 5 : (C == 512 ? 4 : 3); // log2(KC)
    constexpr int NK  = 9 * KC;                               // total k-steps (always even)

    __shared__ short As[2][128 * 32];
    __shared__ short Bs[2][128 * 32];

    // XCD swizzle: consecutive tiles (by fastest) stay on one XCD for A/L2 reuse
    const int lb = blockIdx.x;
    const int tt = (lb & 7) * TPX + (lb >> 3);
    if (tt >= TOT) return;
    const int m0 = (tt / NB) * 128;
    const int n0 = (tt % NB) * 128;

    const int t    = threadIdx.x;
    const int lane = t & 63;
    const int wid  = t >> 6;
    const int lrow = lane >> 2;     // 0..15 row within 16-row load group
    // XOR-swizzle: LDS slot (row, c) holds global 16B-chunk c ^ ((row>>1)&3).
    // GLL dest stays linear (HW requirement); the permutation rides on the
    // per-lane GLOBAL source chunk (m173 pattern):
    const int kqe  = (lane & 3) ^ ((lane >> 3) & 3);

    // per-lane A row addresses + per-tap validity masks (taps hit zero page when invalid)
    const short* abase[2]; unsigned vmask[2];
#pragma unroll
    for (int j = 0; j < 2; ++j) {
        int m = m0 + wid * 32 + j * 16 + lrow;
        int mm = m < M ? m : (M - 1);
        int n = mm / HW;
        int rem = mm - n * HW;
        int y = rem / S, x = rem - (rem / S) * S;
        abase[j] = ft + ((size_t)n * HW + rem) * C + kqe * 8;
        unsigned msk = 0;
#pragma unroll
        for (int r = 0; r < 9; ++r) {
            int dy = r / 3 - 1, dx = r % 3 - 1;
            if ((unsigned)(y + dy) < (unsigned)S && (unsigned)(x + dx) < (unsigned)S)
                msk |= 1u << r;
        }
        vmask[j] = msk;
    }
    // per-lane B row addresses (clamped; stores masked in epilogue)
    const short* bbase[2];
#pragma unroll
    for (int j = 0; j < 2; ++j) {
        int o = n0 + wid * 32 + j * 16 + lrow;
        if (o >= O) o = O - 1;
        bbase[j] = wc + (size_t)o * K + kqe * 8;
    }
    const short* zbl = zb + kqe * 8;

    const int wm    = (wid & 1) * 64;
    const int wn    = (wid >> 1) * 64;
    const int lcol  = lane & 15;
    const int lquad = lane >> 4;
    // swizzled read slot: want global chunk lquad of row (wm|wn)+f*16+lcol;
    // (row>>1)&3 == (lcol>>1)&3 since wm/wn/f*16 are multiples of 16
    const int rq8   = (lquad ^ ((lcol >> 1) & 3)) * 8;

    floatx4 acc[4][4];
#pragma unroll
    for (int i = 0; i < 4; ++i)
#pragma unroll
        for (int j = 0; j < 4; ++j)
#pragma unroll
            for (int q = 0; q < 4; ++q) acc[i][j][q] = 0.f;

    auto stage = [&](int kk, int p) {
        const int r  = kk >> LKC;
        const int c0 = (kk & (KC - 1)) << 5;
        const int dy = r / 3 - 1, dx = r - (r / 3) * 3 - 1;
        const int ro = (dy * S + dx) * C + c0;
        const short* pa0 = ((vmask[0] >> r) & 1) ? abase[0] + ro : zbl + c0;
        const short* pa1 = ((vmask[1] >> r) & 1) ? abase[1] + ro : zbl + c0;
        const short* pb0 = bbase[0] + r * C + c0;
        const short* pb1 = bbase[1] + r * C + c0;
        GLL(pa0, &As[p][(wid * 32 +  0) * 32]);
        GLL(pa1, &As[p][(wid * 32 + 16) * 32]);
        GLL(pb0, &Bs[p][(wid * 32 +  0) * 32]);
        GLL(pb1, &Bs[p][(wid * 32 + 16) * 32]);
    };
    auto compute = [&](int p) {
        short8 af[4], bfr[4];
#pragma unroll
        for (int f = 0; f < 4; ++f) {
            af[f]  = *(const short8*)&As[p][(wm + f * 16 + lcol) * 32 + rq8];
            bfr[f] = *(const short8*)&Bs[p][(wn + f * 16 + lcol) * 32 + rq8];
        }
#pragma unroll
        for (int i = 0; i < 4; ++i)
#pragma unroll
            for (int j = 0; j < 4; ++j)
                acc[i][j] = __builtin_amdgcn_mfma_f32_16x16x32_bf16(af[i], bfr[j], acc[i][j], 0, 0, 0);
    };

    // dbuf pipeline: one barrier per K-step; stage(k+1) flies under compute(k),
    // drained by the trailing __syncthreads (implicit vmcnt(0) before s_barrier)
    stage(0, 0);
    __syncthreads();
#pragma unroll 1
    for (int kk = 0; kk < NK; kk += 2) {
        stage(kk + 1, 1);
        compute(0);
        __syncthreads();
        if (kk + 2 < NK) stage(kk + 2, 0);
        compute(1);
        __syncthreads();
    }

    // ---------------- epilogue: FULLY UNROLLED (all acc indices compile-time!) ----------------
    // dynamic indexing into acc forces it into scratch -> 9 GB/dispatch spill traffic (round 1/2 bug)
    float* const bbox = out;
    float* const cls  = out + CLSOFF;
    int rn[16], rbase[16]; bool rv[16];
#pragma unroll
    for (int fm = 0; fm < 4; ++fm)
#pragma unroll
        for (int rg = 0; rg < 4; ++rg) {
            int idx = fm * 4 + rg;
            int mr = m0 + wm + fm * 16 + lquad * 4 + rg;
            rv[idx] = mr < M;
            int mm = rv[idx] ? mr : 0;
            int n = mm / HW;
            int rem = mm - n * HW;
            rn[idx] = n;
            rbase[idx] = ROWOFF + rem * A;
        }
#pragma unroll
    for (int fn = 0; fn < 4; ++fn) {
        int o = n0 + wn + fn * 16 + lcol;
        if (o < O) {
            if (o < A4) {
                int a = o >> 2, cc = o & 3;
                float bias = reg_b[o];
#pragma unroll
                for (int fm = 0; fm < 4; ++fm)
#pragma unroll
                    for (int rg = 0; rg < 4; ++rg) {
                        int idx = fm * 4 + rg;
                        if (rv[idx])
                            bbox[((size_t)rn[idx] * 8732 + rbase[idx] + a) * 4 + cc] = acc[fm][fn][rg] + bias;
                    }
            } else {
                int oc = o - A4;
                int a = oc / 91, cc = oc - a * 91;
                float bias = cls_b[oc];
#pragma unroll
                for (int fm = 0; fm < 4; ++fm)
#pragma unroll
                    for (int rg = 0; rg < 4; ++rg) {
                        int idx = fm * 4 + rg;
                        if (rv[idx])
                            cls[((size_t)rn[idx] * 8732 + rbase[idx] + a) * 91 + cc] = acc[fm][fn][rg] + bias;
                    }
            }
        }
    }
}

// ---------------- naive fallback (only if ws too small) ----------------
template<int L>
__global__ void naive_conv(const float* __restrict__ feat,
                           const float* __restrict__ cw, const float* __restrict__ cb,
                           const float* __restrict__ rw, const float* __restrict__ rb,
                           float* __restrict__ out)
{
    constexpr int C = LC[L], S = LS[L], A = LA[L];
    constexpr int HW = S * S, M = 32 * HW, A4 = 4 * A, ROWOFF = LROW[L];
    int m = blockIdx.x * 256 + threadIdx.x;
    if (m >= M) return;
    int o = blockIdx.y;
    int n = m / HW, rem = m - n * HW, h = rem / S, w = rem - (rem / S) * S;
    bool isreg = o < A4;
    const float* wr = isreg ? (rw + (size_t)o * C * 9) : (cw + (size_t)(o - A4) * C * 9);
    float sum = isreg ? rb[o] : cb[o - A4];
    const float* fb = feat + (size_t)n * C * HW;
    for (int c = 0; c < C; ++c) {
#pragma unroll
        for (int r = 0; r < 9; ++r) {
            int y = h + r / 3 - 1, x = w + r % 3 - 1;
            if ((unsigned)y < (unsigned)S && (unsigned)x < (unsigned)S)
                sum += wr[c * 9 + r] * fb[(size_t)c * HW + y * S + x];
        }
    }
    int rowidx = ROWOFF + rem * A;
    if (isreg) out[((size_t)n * 8732 + rowidx + (o >> 2)) * 4 + (o & 3)] = sum;
    else {
        int oc = o - A4;
        int a = oc / 91;
        (out + CLSOFF)[((size_t)n * 8732 + rowidx + a) * 91 + (oc - a * 91)] = sum;
    }
}

// ---------------- host ----------------
extern "C" void kernel_launch(void* const* d_in, const int* in_sizes, int n_in,
                              void* d_out, int out_size, void* d_ws, size_t ws_size,
                              hipStream_t stream)
{
    const float *feat[6], *cw[6], *cb[6], *rw[6], *rb[6];
    for (int i = 0; i < 6; ++i) {
        feat[i] = (const float*)d_in[5 * i + 0];
        cw[i]   = (const float*)d_in[5 * i + 1];
        cb[i]   = (const float*)d_in[5 * i + 2];
        rw[i]   = (const float*)d_in[5 * i + 3];
        rb[i]   = (const float*)d_in[5 * i + 4];
    }
    float* out = (float*)d_out;

    if (ws_size >= WS_NEEDED) {
        short* ws  = (short*)d_ws;
        short* wcp = ws + WCBASE;
        short* zb  = ws + ZOFF;
        transpose_feat<0><<<dim3(23, 8, 32), 256, 0, stream>>>(feat[0], ws + FOFF[0]);
        transpose_feat<1><<<dim3(6, 16, 32), 256, 0, stream>>>(feat[1], ws + FOFF[1]);
        transpose_feat<2><<<dim3(2, 8, 32), 256, 0, stream>>>(feat[2], ws + FOFF[2]);
        transpose_feat<3><<<dim3(1, 4, 32), 256, 0, stream>>>(feat[3], ws + FOFF[3]);
        transpose_feat<4><<<dim3(1, 4, 32), 256, 0, stream>>>(feat[4], ws + FOFF[4]);
        transpose_feat<5><<<dim3(1, 4, 32), 256, 0, stream>>>(feat[5], ws + FOFF[5]);
        WPtrs wp;
        for (int i = 0; i < 6; ++i) { wp.cw[i] = cw[i]; wp.rw[i] = rw[i]; }
        reorder_weights<<<6200, 256, 0, stream>>>(wp, wcp, zb);
        // grid = 8 * TPX per level (swizzle-padded): L0:1088 L1:456 L2:128 L3:40 L4:16 L5:8
        gemm_level<0><<<1088, 256, 0, stream>>>(ws + FOFF[0], wcp + WOFF[0], zb, cb[0], rb[0], out);
        gemm_level<1><<<456,  256, 0, stream>>>(ws + FOFF[1], wcp + WOFF[1], zb, cb[1], rb[1], out);
        gemm_level<2><<<128,  256, 0, stream>>>(ws + FOFF[2], wcp + WOFF[2], zb, cb[2], rb[2], out);
        gemm_level<3><<<40,   256, 0, stream>>>(ws + FOFF[3], wcp + WOFF[3], zb, cb[3], rb[3], out);
        gemm_level<4><<<16,   256, 0, stream>>>(ws + FOFF[4], wcp + WOFF[4], zb, cb[4], rb[4], out);
        gemm_level<5><<<8,    256, 0, stream>>>(ws + FOFF[5], wcp + WOFF[5], zb, cb[5], rb[5], out);
    } else {
        naive_conv<0><<<dim3(181, 380), 256, 0, stream>>>(feat[0], cw[0], cb[0], rw[0], rb[0], out);
        naive_conv<1><<<dim3(46, 570),  256, 0, stream>>>(feat[1], cw[1], cb[1], rw[1], rb[1], out);
        naive_conv<2><<<dim3(13, 570),  256, 0, stream>>>(feat[2], cw[2], cb[2], rw[2], rb[2], out);
        naive_conv<3><<<dim3(4, 570),   256, 0, stream>>>(feat[3], cw[3], cb[3], rw[3], rb[3], out);
        naive_conv<4><<<dim3(2, 380),   256, 0, stream>>>(feat[4], cw[4], cb[4], rw[4], rb[4], out);
        naive_conv<5><<<dim3(1, 380),   256, 0, stream>>>(feat[5], cw[5], cb[5], rw[5], rb[5], out);
    }
}

// Round 2
// 1028.967 us; speedup vs baseline: 1.1210x; 1.0850x over previous
//
#include <hip/hip_runtime.h>

typedef __attribute__((ext_vector_type(8))) short short8;
typedef __attribute__((ext_vector_type(4))) float floatx4;

#define DEVI __device__ __forceinline__

// direct global->LDS, 16B per lane; LDS dest = wave-uniform base + lane*16
#define GLL(g, l) __builtin_amdgcn_global_load_lds(                      \
    (const __attribute__((address_space(1))) void*)(g),                  \
    (__attribute__((address_space(3))) void*)(l), 16, 0, 0)

// ---------------- level constants ----------------
constexpr int LC[6]   = {512, 1024, 512, 256, 256, 256};   // in channels
constexpr int LS[6]   = {38, 19, 10, 5, 3, 1};             // spatial
constexpr int LA[6]   = {4, 6, 6, 6, 4, 4};                // anchors
constexpr int LROW[6] = {0, 5776, 7942, 8542, 8692, 8728}; // row offsets into 8732
constexpr long FOFF[6] = {0, 23658496, 35487744, 37126144, 37330944, 37404672}; // featT elem offsets
constexpr long WCBASE  = 37412864;                                              // Wc elem base
constexpr long WOFF[6] = {0, 1751040, 7004160, 9630720, 10944000, 11819520};    // Wc per-level offsets
constexpr int  GOFF[7] = {0, 218880, 875520, 1203840, 1368000, 1477440, 1586880}; // groups of 8
constexpr long ZOFF    = 50107904;   // zero-sentinel page (elems)
constexpr int  ZSIZE   = 1088;
constexpr long CLSOFF  = 1117696;    // 32*8732*4
constexpr size_t WS_NEEDED = (size_t)(ZOFF + ZSIZE) * 2;

DEVI short f2bf(float f) {
    union { float f; unsigned u; } x; x.f = f;
    unsigned u = x.u + 0x7fffu + ((x.u >> 16) & 1u);   // RNE
    return (short)(u >> 16);
}

// ---------------- transpose feat [n,c,pix] f32 -> [n,pix,c] bf16 ----------------
template<int L>
__global__ void transpose_feat(const float* __restrict__ feat, short* __restrict__ ft) {
    constexpr int C = LC[L], S = LS[L], HW = S * S;
    const int n  = blockIdx.z;
    const int p0 = blockIdx.x * 64;
    const int c0 = blockIdx.y * 64;
    __shared__ float tile[64][65];
    const int t = threadIdx.x;
    const float* fb = feat + ((size_t)n * C + c0) * HW;
#pragma unroll
    for (int e = 0; e < 16; ++e) {
        int idx = e * 256 + t;
        int p = idx & 63, cc = idx >> 6;
        int pix = p0 + p;
        tile[cc][p] = (pix < HW) ? fb[(size_t)cc * HW + pix] : 0.f;
    }
    __syncthreads();
    short* ob = ft + ((size_t)n * HW) * C + c0;
#pragma unroll
    for (int e = 0; e < 16; ++e) {
        int idx = e * 256 + t;
        int cc = idx & 63, p = idx >> 6;
        int pix = p0 + p;
        if (pix < HW) ob[(size_t)pix * C + cc] = f2bf(tile[cc][p]);
    }
}

// ---------------- reorder weights: combined [o][k=r*C+c] bf16; also zero-fill sentinel ----------------
struct WPtrs { const float* cw[6]; const float* rw[6]; };

__global__ void reorder_weights(WPtrs p, short* __restrict__ wc, short* __restrict__ zb) {
    int g = blockIdx.x * 256 + threadIdx.x;
    if (g >= GOFF[6]) {
        if (blockIdx.x == 6199 && threadIdx.x < ZSIZE / 8) {
            short8 z;
#pragma unroll
            for (int q = 0; q < 8; ++q) z[q] = 0;
            *(short8*)(zb + threadIdx.x * 8) = z;
        }
        return;
    }
    int L = 0;
#pragma unroll
    for (int q = 1; q < 6; ++q) if (g >= GOFF[q]) L = q;
    int e = g - GOFF[L];
    const int C = LC[L], A = LA[L];
    const unsigned K8 = (unsigned)(9 * C) >> 3, C8 = (unsigned)C >> 3;
    unsigned o    = (unsigned)e / K8;
    unsigned remk = (unsigned)e - o * K8;
    unsigned r    = remk / C8;
    unsigned c    = (remk - r * C8) << 3;
    int A4 = A << 2;
    const float* src = ((int)o < A4) ? (p.rw[L] + (size_t)o * 9 * C)
                                     : (p.cw[L] + (size_t)(o - A4) * 9 * C);
    short8 v;
#pragma unroll
    for (int j = 0; j < 8; ++j) v[j] = f2bf(src[(size_t)(c + j) * 9 + r]);
    *(short8*)(wc + (size_t)WOFF[L] + (size_t)o * (9 * C) + (size_t)r * C + c) = v;
}

// ---------------- implicit-GEMM conv: 3-deep ring, counted-vmcnt pipeline, XOR-swizzled LDS ----------------
template<int L>
__global__ __launch_bounds__(256, 3)
void gemm_level(const short* __restrict__ ft, const short* __restrict__ wc,
                const short* __restrict__ zb,
                const float* __restrict__ cls_b, const float* __restrict__ reg_b,
                float* __restrict__ out)
{
    constexpr int C = LC[L], S = LS[L], A = LA[L];
    constexpr int HW = S * S, M = 32 * HW, K = 9 * C, O = 95 * A;
    constexpr int ROWOFF = LROW[L], A4 = 4 * A;
    constexpr int NM = (M + 127) / 128, NB = (O + 127) / 128;
    constexpr int TOT = NM * NB, TPX = (TOT + 7) / 8;
    constexpr int KC  = C / 32;                               // k-chunks per tap
    constexpr int LKC = (C == 1024) ? 5 : (C == 512 ? 4 : 3); // log2(KC)
    constexpr int NK  = 9 * KC;                               // total k-steps

    __shared__ short As[3][128 * 32];
    __shared__ short Bs[3][128 * 32];

    // XCD swizzle: consecutive tiles (by fastest) stay on one XCD for A/L2 reuse
    const int lb = blockIdx.x;
    const int tt = (lb & 7) * TPX + (lb >> 3);
    if (tt >= TOT) return;
    const int m0 = (tt / NB) * 128;
    const int n0 = (tt % NB) * 128;

    const int t    = threadIdx.x;
    const int lane = t & 63;
    const int wid  = t >> 6;
    const int lrow = lane >> 2;     // 0..15 row within 16-row load group
    // XOR-swizzle: LDS slot (row, c) holds global 16B-chunk c ^ ((row>>1)&3).
    // GLL dest stays linear (HW requirement); the permutation rides on the
    // per-lane GLOBAL source chunk (m173 pattern):
    const int kqe  = (lane & 3) ^ ((lane >> 3) & 3);

    // per-lane A row addresses + per-tap validity masks (taps hit zero page when invalid)
    const short* abase[2]; unsigned vmask[2];
#pragma unroll
    for (int j = 0; j < 2; ++j) {
        int m = m0 + wid * 32 + j * 16 + lrow;
        int mm = m < M ? m : (M - 1);
        int n = mm / HW;
        int rem = mm - n * HW;
        int y = rem / S, x = rem - (rem / S) * S;
        abase[j] = ft + ((size_t)n * HW + rem) * C + kqe * 8;
        unsigned msk = 0;
#pragma unroll
        for (int r = 0; r < 9; ++r) {
            int dy = r / 3 - 1, dx = r % 3 - 1;
            if ((unsigned)(y + dy) < (unsigned)S && (unsigned)(x + dx) < (unsigned)S)
                msk |= 1u << r;
        }
        vmask[j] = msk;
    }
    // per-lane B row addresses (clamped; stores masked in epilogue)
    const short* bbase[2];
#pragma unroll
    for (int j = 0; j < 2; ++j) {
        int o = n0 + wid * 32 + j * 16 + lrow;
        if (o >= O) o = O - 1;
        bbase[j] = wc + (size_t)o * K + kqe * 8;
    }
    const short* zbl = zb + kqe * 8;

    const int wm    = (wid & 1) * 64;
    const int wn    = (wid >> 1) * 64;
    const int lcol  = lane & 15;
    const int lquad = lane >> 4;
    // swizzled read slot: want global chunk lquad of row (wm|wn)+f*16+lcol;
    // (row>>1)&3 == (lcol>>1)&3 since wm/wn/f*16 are multiples of 16
    const int rq8   = (lquad ^ ((lcol >> 1) & 3)) * 8;

    floatx4 acc[4][4];
#pragma unroll
    for (int i = 0; i < 4; ++i)
#pragma unroll
        for (int j = 0; j < 4; ++j)
#pragma unroll
            for (int q = 0; q < 4; ++q) acc[i][j][q] = 0.f;

    auto stage = [&](int kk, int p) {
        const int r  = kk >> LKC;
        const int c0 = (kk & (KC - 1)) << 5;
        const int dy = r / 3 - 1, dx = r - (r / 3) * 3 - 1;
        const int ro = (dy * S + dx) * C + c0;
        const short* pa0 = ((vmask[0] >> r) & 1) ? abase[0] + ro : zbl + c0;
        const short* pa1 = ((vmask[1] >> r) & 1) ? abase[1] + ro : zbl + c0;
        const short* pb0 = bbase[0] + r * C + c0;
        const short* pb1 = bbase[1] + r * C + c0;
        GLL(pa0, &As[p][(wid * 32 +  0) * 32]);
        GLL(pa1, &As[p][(wid * 32 + 16) * 32]);
        GLL(pb0, &Bs[p][(wid * 32 +  0) * 32]);
        GLL(pb1, &Bs[p][(wid * 32 + 16) * 32]);
    };
    auto frags = [&](int p, short8* af, short8* bfr) {
        const short* Ap = &As[p][0];
        const short* Bp = &Bs[p][0];
#pragma unroll
        for (int f = 0; f < 4; ++f) {
            af[f]  = *(const short8*)&Ap[(wm + f * 16 + lcol) * 32 + rq8];
            bfr[f] = *(const short8*)&Bp[(wn + f * 16 + lcol) * 32 + rq8];
        }
    };
    auto mmac = [&](short8* af, short8* bfr) {
#pragma unroll
        for (int i = 0; i < 4; ++i)
#pragma unroll
            for (int j = 0; j < 4; ++j)
                acc[i][j] = __builtin_amdgcn_mfma_f32_16x16x32_bf16(af[i], bfr[j], acc[i][j], 0, 0, 0);
    };

    // ---- counted-vmcnt pipeline: loads never drained to 0 in the main loop ----
    // ring[3]; stage(kk) consumed at iter kk; stage issue for kk+2 each iter.
    // Safety: stage(kk+2) overwrites the buffer read at iter kk-1; those reads are
    // forced delivered by the lgkmcnt(0) before barrier#2 of iter kk-1, and the GLL
    // issue is after that barrier in every wave.
    stage(0, 0);
    stage(1, 1);
    asm volatile("s_waitcnt vmcnt(4)" ::: "memory");   // stage(0) landed
    __builtin_amdgcn_s_barrier();
    int p = 0, pn = 2;
#pragma unroll 1
    for (int kk = 0; kk < NK - 2; ++kk) {
        short8 af[4], bfr[4];
        frags(p, af, bfr);
        stage(kk + 2, pn);
        asm volatile("s_waitcnt vmcnt(4)" ::: "memory");   // stage(kk+1) landed
        __builtin_amdgcn_s_barrier();
        asm volatile("s_waitcnt lgkmcnt(0)" ::: "memory"); // frag reads delivered
        __builtin_amdgcn_s_setprio(1);
        mmac(af, bfr);
        __builtin_amdgcn_s_setprio(0);
        __builtin_amdgcn_s_barrier();
        p  = (p  == 2) ? 0 : p  + 1;
        pn = (pn == 2) ? 0 : pn + 1;
    }
    {   // kk = NK-2: wait the final stage for the NEXT step, no more staging
        short8 af[4], bfr[4];
        frags((NK - 2) % 3, af, bfr);
        asm volatile("s_waitcnt vmcnt(0)" ::: "memory");   // stage(NK-1) landed
        __builtin_amdgcn_s_barrier();
        asm volatile("s_waitcnt lgkmcnt(0)" ::: "memory");
        __builtin_amdgcn_s_setprio(1);
        mmac(af, bfr);
        __builtin_amdgcn_s_setprio(0);
    }
    {   // kk = NK-1: everything resident, no barriers needed
        short8 af[4], bfr[4];
        frags((NK - 1) % 3, af, bfr);
        mmac(af, bfr);
    }

    // ---------------- epilogue: FULLY UNROLLED (all acc indices compile-time!) ----------------
    // dynamic indexing into acc forces it into scratch -> 9 GB/dispatch spill traffic (round 1/2 bug)
    float* const bbox = out;
    float* const cls  = out + CLSOFF;
    int rn[16], rbase[16]; bool rv[16];
#pragma unroll
    for (int fm = 0; fm < 4; ++fm)
#pragma unroll
        for (int rg = 0; rg < 4; ++rg) {
            int idx = fm * 4 + rg;
            int mr = m0 + wm + fm * 16 + lquad * 4 + rg;
            rv[idx] = mr < M;
            int mm = rv[idx] ? mr : 0;
            int n = mm / HW;
            int rem = mm - n * HW;
            rn[idx] = n;
            rbase[idx] = ROWOFF + rem * A;
        }
#pragma unroll
    for (int fn = 0; fn < 4; ++fn) {
        int o = n0 + wn + fn * 16 + lcol;
        if (o < O) {
            if (o < A4) {
                int a = o >> 2, cc = o & 3;
                float bias = reg_b[o];
#pragma unroll
                for (int fm = 0; fm < 4; ++fm)
#pragma unroll
                    for (int rg = 0; rg < 4; ++rg) {
                        int idx = fm * 4 + rg;
                        if (rv[idx])
                            bbox[((size_t)rn[idx] * 8732 + rbase[idx] + a) * 4 + cc] = acc[fm][fn][rg] + bias;
                    }
            } else {
                int oc = o - A4;
                int a = oc / 91, cc = oc - a * 91;
                float bias = cls_b[oc];
#pragma unroll
                for (int fm = 0; fm < 4; ++fm)
#pragma unroll
                    for (int rg = 0; rg < 4; ++rg) {
                        int idx = fm * 4 + rg;
                        if (rv[idx])
                            cls[((size_t)rn[idx] * 8732 + rbase[idx] + a) * 91 + cc] = acc[fm][fn][rg] + bias;
                    }
            }
        }
    }
}

// ---------------- naive fallback (only if ws too small) ----------------
template<int L>
__global__ void naive_conv(const float* __restrict__ feat,
                           const float* __restrict__ cw, const float* __restrict__ cb,
                           const float* __restrict__ rw, const float* __restrict__ rb,
                           float* __restrict__ out)
{
    constexpr int C = LC[L], S = LS[L], A = LA[L];
    constexpr int HW = S * S, M = 32 * HW, A4 = 4 * A, ROWOFF = LROW[L];
    int m = blockIdx.x * 256 + threadIdx.x;
    if (m >= M) return;
    int o = blockIdx.y;
    int n = m / HW, rem = m - n * HW, h = rem / S, w = rem - (rem / S) * S;
    bool isreg = o < A4;
    const float* wr = isreg ? (rw + (size_t)o * C * 9) : (cw + (size_t)(o - A4) * C * 9);
    float sum = isreg ? rb[o] : cb[o - A4];
    const float* fb = feat + (size_t)n * C * HW;
    for (int c = 0; c < C; ++c) {
#pragma unroll
        for (int r = 0; r < 9; ++r) {
            int y = h + r / 3 - 1, x = w + r % 3 - 1;
            if ((unsigned)y < (unsigned)S && (unsigned)x < (unsigned)S)
                sum += wr[c * 9 + r] * fb[(size_t)c * HW + y * S + x];
        }
    }
    int rowidx = ROWOFF + rem * A;
    if (isreg) out[((size_t)n * 8732 + rowidx + (o >> 2)) * 4 + (o & 3)] = sum;
    else {
        int oc = o - A4;
        int a = oc / 91;
        (out + CLSOFF)[((size_t)n * 8732 + rowidx + a) * 91 + (oc - a * 91)] = sum;
    }
}

// ---------------- host ----------------
extern "C" void kernel_launch(void* const* d_in, const int* in_sizes, int n_in,
                              void* d_out, int out_size, void* d_ws, size_t ws_size,
                              hipStream_t stream)
{
    const float *feat[6], *cw[6], *cb[6], *rw[6], *rb[6];
    for (int i = 0; i < 6; ++i) {
        feat[i] = (const float*)d_in[5 * i + 0];
        cw[i]   = (const float*)d_in[5 * i + 1];
        cb[i]   = (const float*)d_in[5 * i + 2];
        rw[i]   = (const float*)d_in[5 * i + 3];
        rb[i]   = (const float*)d_in[5 * i + 4];
    }
    float* out = (float*)d_out;

    if (ws_size >= WS_NEEDED) {
        short* ws  = (short*)d_ws;
        short* wcp = ws + WCBASE;
        short* zb  = ws + ZOFF;
        transpose_feat<0><<<dim3(23, 8, 32), 256, 0, stream>>>(feat[0], ws + FOFF[0]);
        transpose_feat<1><<<dim3(6, 16, 32), 256, 0, stream>>>(feat[1], ws + FOFF[1]);
        transpose_feat<2><<<dim3(2, 8, 32), 256, 0, stream>>>(feat[2], ws + FOFF[2]);
        transpose_feat<3><<<dim3(1, 4, 32), 256, 0, stream>>>(feat[3], ws + FOFF[3]);
        transpose_feat<4><<<dim3(1, 4, 32), 256, 0, stream>>>(feat[4], ws + FOFF[4]);
        transpose_feat<5><<<dim3(1, 4, 32), 256, 0, stream>>>(feat[5], ws + FOFF[5]);
        WPtrs wp;
        for (int i = 0; i < 6; ++i) { wp.cw[i] = cw[i]; wp.rw[i] = rw[i]; }
        reorder_weights<<<6200, 256, 0, stream>>>(wp, wcp, zb);
        // grid = 8 * TPX per level (swizzle-padded): L0:1088 L1:456 L2:128 L3:40 L4:16 L5:8
        gemm_level<0><<<1088, 256, 0, stream>>>(ws + FOFF[0], wcp + WOFF[0], zb, cb[0], rb[0], out);
        gemm_level<1><<<456,  256, 0, stream>>>(ws + FOFF[1], wcp + WOFF[1], zb, cb[1], rb[1], out);
        gemm_level<2><<<128,  256, 0, stream>>>(ws + FOFF[2], wcp + WOFF[2], zb, cb[2], rb[2], out);
        gemm_level<3><<<40,   256, 0, stream>>>(ws + FOFF[3], wcp + WOFF[3], zb, cb[3], rb[3], out);
        gemm_level<4><<<16,   256, 0, stream>>>(ws + FOFF[4], wcp + WOFF[4], zb, cb[4], rb[4], out);
        gemm_level<5><<<8,    256, 0, stream>>>(ws + FOFF[5], wcp + WOFF[5], zb, cb[5], rb[5], out);
    } else {
        naive_conv<0><<<dim3(181, 380), 256, 0, stream>>>(feat[0], cw[0], cb[0], rw[0], rb[0], out);
        naive_conv<1><<<dim3(46, 570),  256, 0, stream>>>(feat[1], cw[1], cb[1], rw[1], rb[1], out);
        naive_conv<2><<<dim3(13, 570),  256, 0, stream>>>(feat[2], cw[2], cb[2], rw[2], rb[2], out);
        naive_conv<3><<<dim3(4, 570),   256, 0, stream>>>(feat[3], cw[3], cb[3], rw[3], rb[3], out);
        naive_conv<4><<<dim3(2, 380),   256, 0, stream>>>(feat[4], cw[4], cb[4], rw[4], rb[4], out);
        naive_conv<5><<<dim3(1, 380),   256, 0, stream>>>(feat[5], cw[5], cb[5], rw[5], rb[5], out);
    }
}

// Round 3
// 715.119 us; speedup vs baseline: 1.6129x; 1.4389x over previous
//
#include <hip/hip_runtime.h>

typedef __attribute__((ext_vector_type(8))) short short8;
typedef __attribute__((ext_vector_type(4))) short short4x;
typedef __attribute__((ext_vector_type(4))) float floatx4;

#define DEVI __device__ __forceinline__

// direct global->LDS, 16B per lane; LDS dest = wave-uniform base + lane*16
#define GLL(g, l) __builtin_amdgcn_global_load_lds(                      \
    (const __attribute__((address_space(1))) void*)(g),                  \
    (__attribute__((address_space(3))) void*)(l), 16, 0, 0)

// ---------------- level constants ----------------
constexpr int LC[6]   = {512, 1024, 512, 256, 256, 256};   // in channels
constexpr int LS[6]   = {38, 19, 10, 5, 3, 1};             // spatial
constexpr int LA[6]   = {4, 6, 6, 6, 4, 4};                // anchors
constexpr int LROW[6] = {0, 5776, 7942, 8542, 8692, 8728}; // row offsets into 8732
constexpr long FOFF[6] = {0, 23658496, 35487744, 37126144, 37330944, 37404672}; // featT elem offsets
constexpr long WCBASE  = 37412864;                                              // Wc elem base
constexpr long WOFF[6] = {0, 1751040, 7004160, 9630720, 10944000, 11819520};    // Wc per-level offsets
constexpr long ZOFF    = 50107904;   // zero-sentinel page (elems)
constexpr int  ZSIZE   = 1088;
constexpr long CLSOFF  = 1117696;    // 32*8732*4
constexpr size_t WS_NEEDED = (size_t)(ZOFF + ZSIZE) * 2;

// reorder: one block per output row o; per-level o counts {380,570,570,570,380,380}
constexpr int RSTART[7] = {0, 380, 950, 1520, 2090, 2470, 2850};
// fused gemm dispatcher: per-level padded grids, small levels first (overlap with big)
// L5:8  L4:8  L3:24  L2:72  L1:232  L0:544  -> total 888
constexpr int GB_T5 = 0, GB_T4 = 8, GB_T3 = 16, GB_T2 = 40, GB_T1 = 112, GB_T0 = 344, GB_TOT = 888;

DEVI short f2bf(float f) {
    union { float f; unsigned u; } x; x.f = f;
    unsigned u = x.u + 0x7fffu + ((x.u >> 16) & 1u);   // RNE
    return (short)(u >> 16);
}

// ---------------- transpose feat [n,c,pix] f32 -> [n,pix,c] bf16 ----------------
template<int L>
__global__ void transpose_feat(const float* __restrict__ feat, short* __restrict__ ft) {
    constexpr int C = LC[L], S = LS[L], HW = S * S;
    const int n  = blockIdx.z;
    const int p0 = blockIdx.x * 64;
    const int c0 = blockIdx.y * 64;
    __shared__ float tile[64][65];
    const int t = threadIdx.x;
    const float* fb = feat + ((size_t)n * C + c0) * HW;
#pragma unroll
    for (int e = 0; e < 16; ++e) {
        int idx = e * 256 + t;
        int p = idx & 63, cc = idx >> 6;
        int pix = p0 + p;
        tile[cc][p] = (pix < HW) ? fb[(size_t)cc * HW + pix] : 0.f;
    }
    __syncthreads();
    short* ob = ft + ((size_t)n * HW) * C + c0;
#pragma unroll
    for (int e = 0; e < 16; ++e) {
        int idx = e * 256 + t;
        int cc = idx & 63, p = idx >> 6;
        int pix = p0 + p;
        if (pix < HW) ob[(size_t)pix * C + cc] = f2bf(tile[cc][p]);
    }
}

// ---------------- reorder weights v2: per-o LDS transpose (coalesced both sides) ----------------
// src row (OIHW flattened): [C][9] f32 ; dst row: [9][C] bf16
struct WPtrs { const float* cw[6]; const float* rw[6]; };

template<int L>
DEVI void reorder_body(int o, const float* cw, const float* rw, short* wc, short* wlds) {
    constexpr int C = LC[L], K9 = 9 * C, A4 = 4 * LA[L];
    constexpr int LC2 = (C == 1024) ? 10 : (C == 512 ? 9 : 8);
    const int tid = threadIdx.x;
    const float* src = (o < A4) ? rw + (size_t)o * K9 : cw + (size_t)(o - A4) * K9;
#pragma unroll 1
    for (int i4 = tid; i4 < K9 / 4; i4 += 256) {
        floatx4 v = *(const floatx4*)(src + 4 * i4);
        short4x s;
#pragma unroll
        for (int j = 0; j < 4; ++j) s[j] = f2bf(v[j]);
        *(short4x*)(wlds + 4 * i4) = s;                 // LDS layout == src layout [C][9]
    }
    __syncthreads();
    short* dst = wc + WOFF[L] + (size_t)o * K9;
#pragma unroll 1
    for (int g = tid; g < K9 / 8; g += 256) {
        const int k0 = g * 8;                           // k = r*C + c
        const int r  = k0 >> LC2;
        const int c0 = k0 & (C - 1);
        short8 v;
#pragma unroll
        for (int j = 0; j < 8; ++j) v[j] = wlds[(c0 + j) * 9 + r];
        *(short8*)(dst + k0) = v;
    }
}

__global__ __launch_bounds__(256)
void reorder_weights2(WPtrs p, short* __restrict__ wc, short* __restrict__ zb) {
    __shared__ short wlds[9216];                        // max 9*1024
    const int b = blockIdx.x;
    if (b >= RSTART[6]) {                               // zero-sentinel page
        if (threadIdx.x < ZSIZE / 8) {
            short8 z;
#pragma unroll
            for (int q = 0; q < 8; ++q) z[q] = 0;
            *(short8*)(zb + threadIdx.x * 8) = z;
        }
        return;
    }
    if (b >= RSTART[5])      reorder_body<5>(b - RSTART[5], p.cw[5], p.rw[5], wc, wlds);
    else if (b >= RSTART[4]) reorder_body<4>(b - RSTART[4], p.cw[4], p.rw[4], wc, wlds);
    else if (b >= RSTART[3]) reorder_body<3>(b - RSTART[3], p.cw[3], p.rw[3], wc, wlds);
    else if (b >= RSTART[2]) reorder_body<2>(b - RSTART[2], p.cw[2], p.rw[2], wc, wlds);
    else if (b >= RSTART[1]) reorder_body<1>(b - RSTART[1], p.cw[1], p.rw[1], wc, wlds);
    else                     reorder_body<0>(b,             p.cw[0], p.rw[0], wc, wlds);
}

// ---------------- implicit-GEMM conv: 256x128 tile, wave 128x64, 3-ring counted-vmcnt ----------------
template<int L>
DEVI void gemm_body(int lb, short* As, short* Bs,
                    const short* ft, const short* wc, const short* zb,
                    const float* cls_b, const float* reg_b, float* out)
{
    constexpr int C = LC[L], S = LS[L], A = LA[L];
    constexpr int HW = S * S, M = 32 * HW, K = 9 * C, O = 95 * A;
    constexpr int ROWOFF = LROW[L], A4 = 4 * A;
    constexpr int NM = (M + 255) / 256, NB = (O + 127) / 128;
    constexpr int TOT = NM * NB, TPX = (TOT + 7) / 8;
    constexpr int KC  = C / 32;
    constexpr int LKC = (C == 1024) ? 5 : (C == 512 ? 4 : 3);
    constexpr int NK  = 9 * KC;

    // XCD swizzle within this level's padded grid
    const int tt = (lb & 7) * TPX + (lb >> 3);
    if (tt >= TOT) return;
    const int m0 = (tt / NB) * 256;
    const int n0 = (tt % NB) * 128;

    const int t    = threadIdx.x;
    const int lane = t & 63;
    const int wid  = t >> 6;
    const int lrow = lane >> 2;
    // XOR-swizzle: LDS slot (row,c) holds global chunk c ^ ((row>>1)&3); GLL dest linear,
    // permutation rides on the per-lane GLOBAL source chunk (m173 pattern):
    const int kqe  = (lane & 3) ^ ((lane >> 3) & 3);

    // A staging: wave stages rows [wid*64, wid*64+64) in 4 groups of 16
    const short* abase[4]; unsigned vmask[4];
#pragma unroll
    for (int j = 0; j < 4; ++j) {
        int m = m0 + wid * 64 + j * 16 + lrow;
        int mm = m < M ? m : (M - 1);
        int n = mm / HW;
        int rem = mm - n * HW;
        int y = rem / S, x = rem - (rem / S) * S;
        abase[j] = ft + ((size_t)n * HW + rem) * C + kqe * 8;
        unsigned msk = 0;
#pragma unroll
        for (int r = 0; r < 9; ++r) {
            int dy = r / 3 - 1, dx = r % 3 - 1;
            if ((unsigned)(y + dy) < (unsigned)S && (unsigned)(x + dx) < (unsigned)S)
                msk |= 1u << r;
        }
        vmask[j] = msk;
    }
    // B staging: wave stages rows [wid*32, wid*32+32) in 2 groups of 16
    const short* bbase[2];
#pragma unroll
    for (int j = 0; j < 2; ++j) {
        int o = n0 + wid * 32 + j * 16 + lrow;
        if (o >= O) o = O - 1;
        bbase[j] = wc + (size_t)o * K + kqe * 8;
    }
    const short* zbl = zb + kqe * 8;

    // compute mapping: 2x2 waves, each owns 128(M) x 64(N)
    const int wm    = (wid & 1) * 128;
    const int wn    = (wid >> 1) * 64;
    const int lcol  = lane & 15;
    const int lquad = lane >> 4;
    const int rq8   = (lquad ^ ((lcol >> 1) & 3)) * 8;   // swizzled read chunk

    floatx4 acc[8][4];
#pragma unroll
    for (int i = 0; i < 8; ++i)
#pragma unroll
        for (int j = 0; j < 4; ++j)
#pragma unroll
            for (int q = 0; q < 4; ++q) acc[i][j][q] = 0.f;

    auto stage = [&](int kk, int p) {
        const int r  = kk >> LKC;
        const int c0 = (kk & (KC - 1)) << 5;
        const int dy = r / 3 - 1, dx = r - (r / 3) * 3 - 1;
        const int roA = (dy * S + dx) * C + c0;
        const int roB = r * C + c0;
        short* ap = As + p * 8192;
        short* bp = Bs + p * 4096;
#pragma unroll
        for (int j = 0; j < 4; ++j) {
            const short* pa = ((vmask[j] >> r) & 1) ? abase[j] + roA : zbl + c0;
            GLL(pa, ap + (wid * 64 + j * 16) * 32);
        }
        GLL(bbase[0] + roB, bp + (wid * 32) * 32);
        GLL(bbase[1] + roB, bp + (wid * 32 + 16) * 32);
    };
    auto frags = [&](int p, short8* af, short8* bfr) {
        const short* ap = As + p * 8192;
        const short* bp = Bs + p * 4096;
#pragma unroll
        for (int f = 0; f < 8; ++f)
            af[f] = *(const short8*)&ap[(wm + f * 16 + lcol) * 32 + rq8];
#pragma unroll
        for (int f = 0; f < 4; ++f)
            bfr[f] = *(const short8*)&bp[(wn + f * 16 + lcol) * 32 + rq8];
    };
    auto mmac = [&](short8* af, short8* bfr) {
#pragma unroll
        for (int i = 0; i < 8; ++i)
#pragma unroll
            for (int j = 0; j < 4; ++j)
                acc[i][j] = __builtin_amdgcn_mfma_f32_16x16x32_bf16(af[i], bfr[j], acc[i][j], 0, 0, 0);
    };

    // counted-vmcnt 3-ring: 6 loads/stage; vmcnt(6) = previous stage landed.
    // Overwrite hazard (stage kk+2 vs reads at kk-1) closed by lgkmcnt(0)+barrier#2 of kk-1.
    stage(0, 0);
    stage(1, 1);
    asm volatile("s_waitcnt vmcnt(6)" ::: "memory");
    __builtin_amdgcn_s_barrier();
    int p = 0, pn = 2;
#pragma unroll 1
    for (int kk = 0; kk < NK - 2; ++kk) {
        short8 af[8], bfr[4];
        frags(p, af, bfr);
        stage(kk + 2, pn);
        asm volatile("s_waitcnt vmcnt(6)" ::: "memory");
        __builtin_amdgcn_s_barrier();
        asm volatile("s_waitcnt lgkmcnt(0)" ::: "memory");
        __builtin_amdgcn_s_setprio(1);
        mmac(af, bfr);
        __builtin_amdgcn_s_setprio(0);
        __builtin_amdgcn_s_barrier();
        p  = (p  == 2) ? 0 : p  + 1;
        pn = (pn == 2) ? 0 : pn + 1;
    }
    {
        short8 af[8], bfr[4];
        frags((NK - 2) % 3, af, bfr);
        asm volatile("s_waitcnt vmcnt(0)" ::: "memory");
        __builtin_amdgcn_s_barrier();
        asm volatile("s_waitcnt lgkmcnt(0)" ::: "memory");
        __builtin_amdgcn_s_setprio(1);
        mmac(af, bfr);
        __builtin_amdgcn_s_setprio(0);
    }
    {
        short8 af[8], bfr[4];
        frags((NK - 1) % 3, af, bfr);
        mmac(af, bfr);
    }

    // ---------------- epilogue: fully static acc indices; row math recomputed (reg-light) ----------------
    float* const bbox = out;
    float* const cls  = out + CLSOFF;
#pragma unroll
    for (int fn = 0; fn < 4; ++fn) {
        const int o = n0 + wn + fn * 16 + lcol;
        if (o < O) {
            if (o < A4) {
                const int aa = o >> 2, cc = o & 3;
                const float bias = reg_b[o];
#pragma unroll
                for (int fm = 0; fm < 8; ++fm)
#pragma unroll
                    for (int rg = 0; rg < 4; ++rg) {
                        int mr = m0 + wm + fm * 16 + lquad * 4 + rg;
                        if (mr < M) {
                            int n = mr / HW, rem = mr - n * HW;
                            bbox[((size_t)n * 8732 + ROWOFF + rem * A + aa) * 4 + cc] = acc[fm][fn][rg] + bias;
                        }
                    }
            } else {
                const int oc = o - A4;
                const int aa = oc / 91, cc = oc - aa * 91;
                const float bias = cls_b[oc];
#pragma unroll
                for (int fm = 0; fm < 8; ++fm)
#pragma unroll
                    for (int rg = 0; rg < 4; ++rg) {
                        int mr = m0 + wm + fm * 16 + lquad * 4 + rg;
                        if (mr < M) {
                            int n = mr / HW, rem = mr - n * HW;
                            cls[((size_t)n * 8732 + ROWOFF + rem * A + aa) * 91 + cc] = acc[fm][fn][rg] + bias;
                        }
                    }
            }
        }
    }
}

struct GArgs {
    const short* ft[6];
    const short* wcL[6];
    const short* zb;
    const float* cb[6];
    const float* rb[6];
    float* out;
};

__global__ __launch_bounds__(256, 2)
void gemm_all(GArgs a) {
    __shared__ __align__(16) short As[3 * 8192];   // 256 rows x 32, 3-ring (48 KB)
    __shared__ __align__(16) short Bs[3 * 4096];   // 128 rows x 32, 3-ring (24 KB)
    const int b = blockIdx.x;
    if (b >= GB_T0)      gemm_body<0>(b - GB_T0, As, Bs, a.ft[0], a.wcL[0], a.zb, a.cb[0], a.rb[0], a.out);
    else if (b >= GB_T1) gemm_body<1>(b - GB_T1, As, Bs, a.ft[1], a.wcL[1], a.zb, a.cb[1], a.rb[1], a.out);
    else if (b >= GB_T2) gemm_body<2>(b - GB_T2, As, Bs, a.ft[2], a.wcL[2], a.zb, a.cb[2], a.rb[2], a.out);
    else if (b >= GB_T3) gemm_body<3>(b - GB_T3, As, Bs, a.ft[3], a.wcL[3], a.zb, a.cb[3], a.rb[3], a.out);
    else if (b >= GB_T4) gemm_body<4>(b - GB_T4, As, Bs, a.ft[4], a.wcL[4], a.zb, a.cb[4], a.rb[4], a.out);
    else                 gemm_body<5>(b - GB_T5, As, Bs, a.ft[5], a.wcL[5], a.zb, a.cb[5], a.rb[5], a.out);
}

// ---------------- naive fallback (only if ws too small) ----------------
template<int L>
__global__ void naive_conv(const float* __restrict__ feat,
                           const float* __restrict__ cw, const float* __restrict__ cb,
                           const float* __restrict__ rw, const float* __restrict__ rb,
                           float* __restrict__ out)
{
    constexpr int C = LC[L], S = LS[L], A = LA[L];
    constexpr int HW = S * S, M = 32 * HW, A4 = 4 * A, ROWOFF = LROW[L];
    int m = blockIdx.x * 256 + threadIdx.x;
    if (m >= M) return;
    int o = blockIdx.y;
    int n = m / HW, rem = m - n * HW, h = rem / S, w = rem - (rem / S) * S;
    bool isreg = o < A4;
    const float* wr = isreg ? (rw + (size_t)o * C * 9) : (cw + (size_t)(o - A4) * C * 9);
    float sum = isreg ? rb[o] : cb[o - A4];
    const float* fb = feat + (size_t)n * C * HW;
    for (int c = 0; c < C; ++c) {
#pragma unroll
        for (int r = 0; r < 9; ++r) {
            int y = h + r / 3 - 1, x = w + r % 3 - 1;
            if ((unsigned)y < (unsigned)S && (unsigned)x < (unsigned)S)
                sum += wr[c * 9 + r] * fb[(size_t)c * HW + y * S + x];
        }
    }
    int rowidx = ROWOFF + rem * A;
    if (isreg) out[((size_t)n * 8732 + rowidx + (o >> 2)) * 4 + (o & 3)] = sum;
    else {
        int oc = o - A4;
        int a = oc / 91;
        (out + CLSOFF)[((size_t)n * 8732 + rowidx + a) * 91 + (oc - a * 91)] = sum;
    }
}

// ---------------- host ----------------
extern "C" void kernel_launch(void* const* d_in, const int* in_sizes, int n_in,
                              void* d_out, int out_size, void* d_ws, size_t ws_size,
                              hipStream_t stream)
{
    const float *feat[6], *cw[6], *cb[6], *rw[6], *rb[6];
    for (int i = 0; i < 6; ++i) {
        feat[i] = (const float*)d_in[5 * i + 0];
        cw[i]   = (const float*)d_in[5 * i + 1];
        cb[i]   = (const float*)d_in[5 * i + 2];
        rw[i]   = (const float*)d_in[5 * i + 3];
        rb[i]   = (const float*)d_in[5 * i + 4];
    }
    float* out = (float*)d_out;

    if (ws_size >= WS_NEEDED) {
        short* ws  = (short*)d_ws;
        short* wcp = ws + WCBASE;
        short* zb  = ws + ZOFF;
        transpose_feat<0><<<dim3(23, 8, 32), 256, 0, stream>>>(feat[0], ws + FOFF[0]);
        transpose_feat<1><<<dim3(6, 16, 32), 256, 0, stream>>>(feat[1], ws + FOFF[1]);
        transpose_feat<2><<<dim3(2, 8, 32), 256, 0, stream>>>(feat[2], ws + FOFF[2]);
        transpose_feat<3><<<dim3(1, 4, 32), 256, 0, stream>>>(feat[3], ws + FOFF[3]);
        transpose_feat<4><<<dim3(1, 4, 32), 256, 0, stream>>>(feat[4], ws + FOFF[4]);
        transpose_feat<5><<<dim3(1, 4, 32), 256, 0, stream>>>(feat[5], ws + FOFF[5]);
        WPtrs wp;
        for (int i = 0; i < 6; ++i) { wp.cw[i] = cw[i]; wp.rw[i] = rw[i]; }
        reorder_weights2<<<RSTART[6] + 1, 256, 0, stream>>>(wp, wcp, zb);
        GArgs ga;
        for (int i = 0; i < 6; ++i) {
            ga.ft[i]  = ws + FOFF[i];
            ga.wcL[i] = wcp + WOFF[i];
            ga.cb[i]  = cb[i];
            ga.rb[i]  = rb[i];
        }
        ga.zb  = zb;
        ga.out = out;
        gemm_all<<<GB_TOT, 256, 0, stream>>>(ga);
    } else {
        naive_conv<0><<<dim3(181, 380), 256, 0, stream>>>(feat[0], cw[0], cb[0], rw[0], rb[0], out);
        naive_conv<1><<<dim3(46, 570),  256, 0, stream>>>(feat[1], cw[1], cb[1], rw[1], rb[1], out);
        naive_conv<2><<<dim3(13, 570),  256, 0, stream>>>(feat[2], cw[2], cb[2], rw[2], rb[2], out);
        naive_conv<3><<<dim3(4, 570),   256, 0, stream>>>(feat[3], cw[3], cb[3], rw[3], rb[3], out);
        naive_conv<4><<<dim3(2, 380),   256, 0, stream>>>(feat[4], cw[4], cb[4], rw[4], rb[4], out);
        naive_conv<5><<<dim3(1, 380),   256, 0, stream>>>(feat[5], cw[5], cb[5], rw[5], rb[5], out);
    }
}